// Round 7
// baseline (133.914 us; speedup 1.0000x reference)
//
#include <hip/hip_runtime.h>
#include <stdint.h>

#define NXS 8192
#define HS  1024

typedef __attribute__((ext_vector_type(8))) short short8;
typedef __attribute__((ext_vector_type(4))) float f32x4;

__device__ __forceinline__ float bf2f(uint32_t b) {
    union { uint32_t u; float f; } c; c.u = b << 16; return c.f;
}
__device__ __forceinline__ uint16_t f2bf(float f) {
    union { float f; uint32_t u; } c; c.f = f;
    return (uint16_t)((c.u + 0x7fffu + ((c.u >> 16) & 1u)) >> 16);
}
// fast tanh: 1 - 2/(e^{2x}+1); |err| ~1e-5 << bf16 quantum; clamp +-15.
__device__ __forceinline__ float fast_tanh(float x) {
    float xc = fminf(fmaxf(x, -15.f), 15.f);
    return 1.f - __fdividef(2.f, __expf(2.f * xc) + 1.f);
}
__device__ __forceinline__ void async_cp16(const void* g, void* l) {
    __builtin_amdgcn_global_load_lds(
        (const __attribute__((address_space(1))) void*)g,
        (__attribute__((address_space(3))) void*)l,
        16, 0, 0);
}

// ---- K01: merged prep (unchanged from round 6) ----
__global__ __launch_bounds__(256) void k01(
    const float* __restrict__ x, const float* __restrict__ W1,
    const float* __restrict__ b1, const float* __restrict__ W2,
    const float* __restrict__ b3, uint16_t* __restrict__ Z1,
    uint16_t* __restrict__ Bp1, uint16_t* __restrict__ Bp2,
    uint16_t* __restrict__ W1T, float* __restrict__ out)
{
    __shared__ float xs[8][8];
    const int b = blockIdx.x, t = threadIdx.x;
    if (b < 1024) {
        const int n0 = b * 8;
        if (t < 64) xs[t >> 3][t & 7] = x[n0 * 8 + t];
        const int j = t * 4;
        float w[4][8];
#pragma unroll
        for (int c = 0; c < 4; ++c) {
            float4 w0 = *(const float4*)(W1 + (j + c) * 8);
            float4 w1 = *(const float4*)(W1 + (j + c) * 8 + 4);
            w[c][0] = w0.x; w[c][1] = w0.y; w[c][2] = w0.z; w[c][3] = w0.w;
            w[c][4] = w1.x; w[c][5] = w1.y; w[c][6] = w1.z; w[c][7] = w1.w;
        }
        float4 bb = *(const float4*)(b1 + j);
        const float bv[4] = {bb.x, bb.y, bb.z, bb.w};
        __syncthreads();
#pragma unroll
        for (int s = 0; s < 8; ++s) {
            ushort4 o;
            uint16_t* op = (uint16_t*)&o;
#pragma unroll
            for (int c = 0; c < 4; ++c) {
                float sum = bv[c];
#pragma unroll
                for (int k = 0; k < 8; ++k) sum += xs[s][k] * w[c][k];
                op[c] = f2bf(fast_tanh(sum));
            }
            *(ushort4*)(Z1 + (size_t)(n0 + s) * HS + j) = o;
        }
    } else if (b < 1536) {
        const int tid = (b - 1024) * 256 + t;            // 0..131071
        const int l = tid & 63, c = (tid >> 6) & 31, g = tid >> 11;
        const int lr = l & 15, lq = l >> 4;
        const float* src = W2 + (size_t)(g * 16 + lr) * HS + c * 32 + lq * 8;
        float4 a0 = *(const float4*)src;
        float4 a1 = *(const float4*)(src + 4);
        uint16_t o[8];
        o[0] = f2bf(a0.x); o[1] = f2bf(a0.y); o[2] = f2bf(a0.z); o[3] = f2bf(a0.w);
        o[4] = f2bf(a1.x); o[5] = f2bf(a1.y); o[6] = f2bf(a1.z); o[7] = f2bf(a1.w);
        *(ushort4*)(Bp1 + (size_t)tid * 8)     = *(ushort4*)&o[0];
        *(ushort4*)(Bp1 + (size_t)tid * 8 + 4) = *(ushort4*)&o[4];
    } else if (b < 2048) {
        const int tid = (b - 1536) * 256 + t;
        const int l = tid & 63, c = (tid >> 6) & 31, g = tid >> 11;
        const int lr = l & 15, lq = l >> 4;
        uint16_t o[8];
#pragma unroll
        for (int j2 = 0; j2 < 8; ++j2)
            o[j2] = f2bf(W2[(size_t)(c * 32 + lq * 8 + j2) * HS + g * 16 + lr]);
        *(ushort4*)(Bp2 + (size_t)tid * 8)     = *(ushort4*)&o[0];
        *(ushort4*)(Bp2 + (size_t)tid * 8 + 4) = *(ushort4*)&o[4];
    } else if (b < 2336) {
        const int idx = (b - 2048) * 256 + t;            // 0..73727
        out[idx] = (idx < NXS) ? b3[0] : 0.f;
    } else {
        const int idx = (b - 2336) * 256 + t;            // 0..16383
        const int r = idx >> 10, cc = idx & 1023;
        W1T[idx] = (r < 8) ? f2bf(W1[cc * 8 + r]) : (uint16_t)0;
    }
}

// -------- GEMM: 64x128 tile, 4 waves, BK=32, A+B both via global_load_lds,
// LDS double-buffered 2 x (A 4KB + B 8KB) = 24 KB -> grid 1024 blocks =
// 4 blocks/CU = 4 waves/SIMD. Plain __syncthreads 2-phase (m97 structure):
// the per-step vmcnt(0) drain is covered by the 3 other co-resident blocks
// (m114 cross-block overlap), which rounds 5/6 (2 blocks/CU) could not do.
// A swizzle: LDS[rA][sl] holds global slot sl^((rA>>1)&3); 64B row stride
// puts row parity in the bank index -> 16 lanes spread over 8 bank-windows,
// 2-way = free. B: 8 chunks of 1KB per step, linear; per-wave contiguous
// ds_read_b128.
// Wave w owns rows[0,64) x cols [w*32,+32): acc[4][2].
// MODE 0: C = Z1 @ W2^T (Bp1); epilogue: tanh -> V (bf16), y atomics
// MODE 1: C = U = V @ W2 (Bp2); fused MFMA dydx epilogue via W1T
template <int MODE>
__global__ __launch_bounds__(256, 4) void gemm_k(
    const uint16_t* __restrict__ A, const uint16_t* __restrict__ Bp,
    const float* __restrict__ bias, const float* __restrict__ W3,
    uint16_t* __restrict__ Out, float* __restrict__ yOut,
    const uint16_t* __restrict__ Z1, const uint16_t* __restrict__ W1T,
    float* __restrict__ dOut)
{
    // dbuf: buf b at u16 [b*6144, +6144): A [0,2048), B [2048,6144).
    // MODE1 epilogue c-matrix 64x136 = 8704 u16 < 12288.
    __shared__ __attribute__((aligned(16))) uint16_t smem[12288];  // 24 KB
    const int t = threadIdx.x;
    const int wave = t >> 6, lane = t & 63;
    const int lq = lane >> 4, lr = lane & 15;
    const int rowBase = blockIdx.x * 64;
    const int colBase = blockIdx.y * 128;

    // A staging: 256 segs/step (64 rows x 4 slots), 1 per thread.
    // Source slot pre-swizzled q = sl ^ ((rA>>1)&3); LDS dest linear t*16B.
    const uint16_t* gA;
    {
        int rA = t >> 2, q = (t & 3) ^ ((rA >> 1) & 3);
        gA = A + (size_t)(rowBase + rA) * HS + q * 8;
    }
    // B staging: 512 segs/step (8 chunks x 64 lanes), 2 per thread.
    // Chunk (g,c) at (g*32+c)*512 u16 in Bp; step advance +512.
    const uint16_t* gB0;
    const uint16_t* gB1;
    {
        int s0 = t, s1 = t + 256;
        gB0 = Bp + ((size_t)(colBase >> 4) + (s0 >> 6)) * 16384 + (size_t)(s0 & 63) * 8;
        gB1 = Bp + ((size_t)(colBase >> 4) + (s1 >> 6)) * 16384 + (size_t)(s1 & 63) * 8;
    }

    f32x4 acc[4][2] = {};

    // prologue: stage step 0 -> buf0
    async_cp16(gA,  (char*)smem + t * 16);
    async_cp16(gB0, (char*)smem + 4096 + t * 16);
    async_cp16(gB1, (char*)smem + 8192 + t * 16);
    __syncthreads();

    int buf = 0;
    for (int c = 0; c < 32; ++c) {
        if (c < 31) {
            char* d = (char*)smem + (buf ^ 1) * 12288;
            async_cp16(gA + (c + 1) * 32,        d + t * 16);
            async_cp16(gB0 + (size_t)(c + 1) * 512, d + 4096 + t * 16);
            async_cp16(gB1 + (size_t)(c + 1) * 512, d + 8192 + t * 16);
        }
        const uint16_t* pA = smem + buf * 6144;
        const uint16_t* pB = pA + 2048;
        short8 bfrag[2];
#pragma unroll
        for (int tj = 0; tj < 2; ++tj)
            bfrag[tj] = *(const short8*)(pB + (((wave << 1) + tj) * 64 + lane) * 8);
        short8 af[4];
#pragma unroll
        for (int ti = 0; ti < 4; ++ti) {
            int ar = ti * 16 + lr;
            af[ti] = *(const short8*)(pA + ar * 32
                      + ((lq ^ ((ar >> 1) & 3)) << 3));
        }
#pragma unroll
        for (int ti = 0; ti < 4; ++ti)
#pragma unroll
            for (int tj = 0; tj < 2; ++tj)
                acc[ti][tj] = __builtin_amdgcn_mfma_f32_16x16x32_bf16(
                    af[ti], bfrag[tj], acc[ti][tj], 0, 0, 0);
        __syncthreads();
        buf ^= 1;
    }

    if (MODE == 0) {
        float cB[2], cW[2]; int cCol[2];
#pragma unroll
        for (int tj = 0; tj < 2; ++tj) {
            cCol[tj] = colBase + wave * 32 + tj * 16 + lr;
            cB[tj] = bias[cCol[tj]];
            cW[tj] = W3[cCol[tj]];
        }
#pragma unroll
        for (int ti = 0; ti < 4; ++ti) {
#pragma unroll
            for (int r = 0; r < 4; ++r) {
                int row = rowBase + ti * 16 + lq * 4 + r;
                float ys = 0.f;
#pragma unroll
                for (int tj = 0; tj < 2; ++tj) {
                    float z2 = fast_tanh(acc[ti][tj][r] + cB[tj]);
                    ys += z2 * cW[tj];
                    Out[(size_t)row * HS + cCol[tj]] = f2bf((1.f - z2 * z2) * cW[tj]);
                }
                ys += __shfl_xor(ys, 1); ys += __shfl_xor(ys, 2);
                ys += __shfl_xor(ys, 4); ys += __shfl_xor(ys, 8);
                if (lr == 0) atomicAdd(&yOut[row], ys);
            }
        }
    } else {
        // c = U*(1-z1^2) -> LDS [64 rows][stride 136 u16]
#pragma unroll
        for (int ti = 0; ti < 4; ++ti)
#pragma unroll
            for (int r = 0; r < 4; ++r) {
                int rowl = ti * 16 + lq * 4 + r;
                const size_t zrow = (size_t)(rowBase + rowl) * HS + colBase;
#pragma unroll
                for (int tj = 0; tj < 2; ++tj) {
                    int coll = wave * 32 + tj * 16 + lr;
                    float z1 = bf2f(Z1[zrow + coll]);
                    smem[rowl * 136 + coll] =
                        f2bf(acc[ti][tj][r] * (1.f - z1 * z1));
                }
            }
        __syncthreads();
        // D[16x8 per wave] = c-rows [wave*16,+16) @ W1T-slice, via 4 MFMAs
        f32x4 dd = {};
#pragma unroll
        for (int kb = 0; kb < 4; ++kb) {
            short8 aF = *(const short8*)(smem + (wave * 16 + lr) * 136
                                         + kb * 32 + lq * 8);
            short8 bF = *(const short8*)(W1T + (size_t)lr * HS + colBase
                                         + kb * 32 + lq * 8);
            dd = __builtin_amdgcn_mfma_f32_16x16x32_bf16(aF, bF, dd, 0, 0, 0);
        }
        if (lr < 8) {
            int row = rowBase + wave * 16 + lq * 4;
#pragma unroll
            for (int rg = 0; rg < 4; ++rg)
                atomicAdd(&dOut[(size_t)lr * NXS + row + rg], dd[rg]);
        }
    }
}

extern "C" void kernel_launch(void* const* d_in, const int* in_sizes, int n_in,
                              void* d_out, int out_size, void* d_ws, size_t ws_size,
                              hipStream_t stream) {
    (void)in_sizes; (void)n_in; (void)out_size; (void)ws_size;
    const float* x  = (const float*)d_in[0];
    const float* W1 = (const float*)d_in[1];
    const float* b1 = (const float*)d_in[2];
    const float* W2 = (const float*)d_in[3];
    const float* b2 = (const float*)d_in[4];
    const float* W3 = (const float*)d_in[5];
    const float* b3 = (const float*)d_in[6];
    float* out = (float*)d_out;

    char* ws = (char*)d_ws;
    // ws layout:
    //   [0, 16MB)     Z1 bf16 (live through GEMM2's epilogue)
    //   [16MB, 32MB)  V bf16
    //   [32MB, 34MB)  Bp1 bf16 fragment-packed W2   (GEMM1 B)
    //   [34MB, 36MB)  Bp2 bf16 fragment-packed W2^T (GEMM2 B)
    //   [36MB, +32KB) W1T bf16 [16][1024] (rows 8..15 zero)
    uint16_t* Z1  = (uint16_t*)(ws);
    uint16_t* V   = (uint16_t*)(ws + (size_t)16 * 1024 * 1024);
    uint16_t* Bp1 = (uint16_t*)(ws + (size_t)32 * 1024 * 1024);
    uint16_t* Bp2 = (uint16_t*)(ws + (size_t)34 * 1024 * 1024);
    uint16_t* W1T = (uint16_t*)(ws + (size_t)36 * 1024 * 1024);

    k01<<<2400, 256, 0, stream>>>(x, W1, b1, W2, b3, Z1, Bp1, Bp2, W1T, out);
    gemm_k<0><<<dim3(NXS / 64, HS / 128), 256, 0, stream>>>(
        Z1, Bp1, b2, W3, V, out, nullptr, nullptr, nullptr);
    gemm_k<1><<<dim3(NXS / 64, HS / 128), 256, 0, stream>>>(
        V, Bp2, nullptr, nullptr, nullptr, nullptr, Z1, W1T, out + NXS);
}